// Round 2
// baseline (351.410 us; speedup 1.0000x reference)
//
#include <hip/hip_runtime.h>

// ---------------------------------------------------------------------------
// DeepseekV3 MoE: T=2048 tokens, H=1024, E=16 experts (top-4), I=512, SI=1024
// 5 dispatches: route+convert, mega-transpose, up-GEMM (routed+shared, dual,
// silu*u), down-GEMM (routed+shared), combine. bf16 MFMA, fp32 routing.
// ---------------------------------------------------------------------------

#define T_TOK 2048
#define H_DIM 1024
#define E_NUM 16
#define I_DIM 512
#define SI_DIM 1024

typedef __bf16 bf16x8 __attribute__((ext_vector_type(8)));
typedef short short8 __attribute__((ext_vector_type(8)));
typedef float f32x4 __attribute__((ext_vector_type(4)));
typedef unsigned short u16;

struct alignas(8) U16x4 { u16 x, y, z, w; };
struct alignas(4) U16x2 { u16 x, y; };

__device__ __forceinline__ float bf2f(u16 u) {
    union { float f; unsigned int i; } v; v.i = ((unsigned int)u) << 16; return v.f;
}
__device__ __forceinline__ u16 f2bf(float f) {
    union { float f; unsigned int i; } v; v.f = f;
    unsigned int i = v.i;
    return (u16)((i + 0x7fffu + ((i >> 16) & 1u)) >> 16);   // RNE
}

#define GLOAD16(g, l)                                                          \
    __builtin_amdgcn_global_load_lds(                                          \
        (const __attribute__((address_space(1))) unsigned int*)(const void*)(g),\
        (__attribute__((address_space(3))) unsigned int*)(void*)(l), 16, 0, 0)

#define CNT(e) ((e) * 16)   // counts padded to one cacheline each

// ---------------------------------------------------------------------------
// K1: routing + x->bf16. One wave per token.
// ---------------------------------------------------------------------------
__global__ __launch_bounds__(256) void route_kernel(
    const float* __restrict__ x, const float* __restrict__ gw,
    int* __restrict__ cnt, int* __restrict__ tok,
    int* __restrict__ slot, float* __restrict__ wgt, u16* __restrict__ xb)
{
    const int wid  = threadIdx.x >> 6;
    const int lane = threadIdx.x & 63;
    const int t    = blockIdx.x * 4 + wid;

    const float* xp = x + (long)t * H_DIM;
    float xr[16];
#pragma unroll
    for (int j = 0; j < 16; ++j) xr[j] = xp[lane + 64 * j];

    // fused convert: write bf16 row (coalesced 128B segments per j)
#pragma unroll
    for (int j = 0; j < 16; ++j) xb[(long)t * H_DIM + lane + 64 * j] = f2bf(xr[j]);

    float sc[E_NUM];
#pragma unroll
    for (int e = 0; e < E_NUM; ++e) {
        const float* gp = gw + e * H_DIM;
        float d = 0.f;
#pragma unroll
        for (int j = 0; j < 16; ++j) d += xr[j] * gp[lane + 64 * j];
#pragma unroll
        for (int off = 32; off; off >>= 1) d += __shfl_xor(d, off);
        sc[e] = 1.f / (1.f + expf(-d));      // sigmoid
    }

    // top-4, strict > so ties pick lowest index (matches jax top_k)
    float w[4]; int id[4];
    unsigned picked = 0;
    float sum = 0.f;
#pragma unroll
    for (int k = 0; k < 4; ++k) {
        float mv = -1.f; int mi = 0;
#pragma unroll
        for (int e = 0; e < E_NUM; ++e) {
            bool ok = !((picked >> e) & 1u) && (sc[e] > mv);
            mv = ok ? sc[e] : mv;
            mi = ok ? e : mi;
        }
        w[k] = mv; id[k] = mi; picked |= 1u << mi; sum += mv;
    }
    const float inv = 1.f / (sum + 1e-20f);

    if (lane == 0) {
#pragma unroll
        for (int k = 0; k < 4; ++k) {
            int pos = atomicAdd(&cnt[CNT(id[k])], 1);
            tok[id[k] * T_TOK + pos] = t;
            slot[t * 4 + k] = (id[k] << 16) | pos;
            wgt[t * 4 + k]  = w[k] * inv;
        }
    }
}

// ---------------------------------------------------------------------------
// K2: mega transpose-convert. Six tensors [batch][R][C] f32 -> [batch][C][R]
// bf16 in one flat grid; 64x64 tiles in LDS (pad stride 65).
// ---------------------------------------------------------------------------
__device__ __forceinline__ void tr_tile(
    const float* __restrict__ in, u16* __restrict__ out,
    int R, int C, int z, int by, int bx)
{
    __shared__ float tl[64][65];
    const long boff = (long)z * R * C;
    const int r0 = by * 64, c0 = bx * 64;
    const int tid = threadIdx.x;

#pragma unroll
    for (int p = 0; p < 16; ++p) {
        int row = p * 4 + (tid >> 6), col = tid & 63;
        tl[row][col] = in[boff + (long)(r0 + row) * C + (c0 + col)];
    }
    __syncthreads();
#pragma unroll
    for (int p = 0; p < 8; ++p) {
        int cc = p * 8 + (tid >> 5), rp = (tid & 31) * 2;
        U16x2 o = { f2bf(tl[rp][cc]), f2bf(tl[rp + 1][cc]) };
        *(U16x2*)&out[boff + (long)(c0 + cc) * R + (r0 + rp)] = o;
    }
}

__global__ __launch_bounds__(256) void transpose_mega(
    const float* __restrict__ eg, const float* __restrict__ eu,
    const float* __restrict__ ed, const float* __restrict__ sg,
    const float* __restrict__ su, const float* __restrict__ sd,
    u16* __restrict__ egT, u16* __restrict__ euT, u16* __restrict__ edT,
    u16* __restrict__ sgT, u16* __restrict__ suT, u16* __restrict__ sdT)
{
    int b = blockIdx.x;
    if (b < 2048) {                       // eg: R=1024 C=512, 128 blocks/expert
        int z = b >> 7, rem = b & 127;
        tr_tile(eg, egT, H_DIM, I_DIM, z, rem >> 3, rem & 7);
    } else if (b < 4096) {                // eu
        int l = b - 2048; int z = l >> 7, rem = l & 127;
        tr_tile(eu, euT, H_DIM, I_DIM, z, rem >> 3, rem & 7);
    } else if (b < 6144) {                // ed: R=512 C=1024
        int l = b - 4096; int z = l >> 7, rem = l & 127;
        tr_tile(ed, edT, I_DIM, H_DIM, z, rem >> 4, rem & 15);
    } else if (b < 6400) {                // sg: 1024x1024
        int l = b - 6144;
        tr_tile(sg, sgT, H_DIM, SI_DIM, 0, l >> 4, l & 15);
    } else if (b < 6656) {                // su
        int l = b - 6400;
        tr_tile(su, suT, H_DIM, SI_DIM, 0, l >> 4, l & 15);
    } else {                              // sd
        int l = b - 6656;
        tr_tile(sd, sdT, SI_DIM, H_DIM, 0, l >> 4, l & 15);
    }
}

// ---------------------------------------------------------------------------
// K3/K4: unified MoE GEMM. Tile 128x64, BK=64, 4 waves (2x2), double-buffered
// LDS, chunk-XOR swizzle on both sides. MODE 0 = up (dual B, silu(g)*u,
// routed->actR / shared->actS, both bf16). MODE 1 = down (routed->pair bf16,
// shared->out fp32). m-fastest flat grid + bijective XCD swizzle.
// ---------------------------------------------------------------------------
template<int MODE>
__global__ __launch_bounds__(256) void gemm_moe(
    const u16* __restrict__ xb, const u16* __restrict__ actR,
    const u16* __restrict__ actS,
    const u16* __restrict__ Wr1, const u16* __restrict__ Wr2,
    const u16* __restrict__ Ws1, const u16* __restrict__ Ws2,
    u16* __restrict__ outR, void* __restrict__ outS,
    const int* __restrict__ cnt, const int* __restrict__ tok)
{
    constexpr bool DUAL  = (MODE == 0);
    constexpr int  NWG   = (MODE == 0) ? 2304 : 4352;
    constexpr int  CPX   = NWG / 8;
    constexpr int  RB    = (MODE == 0) ? 2048 : 4096;   // routed block count
    constexpr int  PER_E = RB / E_NUM;

    const int bswz = blockIdx.x;
    const int idx  = (bswz & 7) * CPX + (bswz >> 3);    // XCD-chunk swizzle

    const bool routed = idx < RB;
    int e = 0, mb, nb;
    if (routed) {
        e = idx / PER_E;
        int rem = idx % PER_E;
        nb = rem >> 4;                                   // m fastest
        mb = rem & 15;
    } else {
        int rem = idx - RB;
        nb = rem >> 4;
        mb = rem & 15;
    }

    int M, K, Ntot, rbase = 0;
    const u16 *Ap, *B1p, *B2p = nullptr;
    if (routed) {
        M = cnt[CNT(e)];
#pragma unroll
        for (int i = 0; i < E_NUM; ++i) rbase += (i < e) ? cnt[CNT(i)] : 0;
        K    = (MODE == 0) ? H_DIM : I_DIM;
        Ntot = (MODE == 0) ? I_DIM : H_DIM;
        Ap   = (MODE == 0) ? xb : actR;
        B1p  = Wr1 + (long)e * (512L * 1024L);
        if (DUAL) B2p = Wr2 + (long)e * (512L * 1024L);
    } else {
        M = T_TOK; K = (MODE == 0) ? H_DIM : SI_DIM;
        Ntot = (MODE == 0) ? SI_DIM : H_DIM;
        Ap = (MODE == 0) ? xb : actS;
        B1p = Ws1; if (DUAL) B2p = Ws2;
    }
    const int m0 = mb * 128;
    if (m0 >= M) return;
    const int n0 = nb * 64;

    __shared__ __attribute__((aligned(16))) u16 sA[2][128 * 64];
    __shared__ __attribute__((aligned(16))) u16 sB1[2][64 * 64];
    __shared__ __attribute__((aligned(16))) u16 sB2[DUAL ? 2 : 1][DUAL ? 64 * 64 : 8];

    const int tid  = threadIdx.x;
    const int lane = tid & 63;
    const int wid  = tid >> 6;
    const int wr   = wid >> 1;
    const int wc   = wid & 1;

    // staging source pointers: slot q -> (row=q>>3, phys chunk s=q&7); the
    // global chunk fetched is s^(row&7) so linear LDS ends up chunk-swizzled.
    const u16* aptr[4];
#pragma unroll
    for (int i = 0; i < 4; ++i) {
        int q = i * 256 + tid;
        int row = q >> 3, s = q & 7;
        int r = m0 + row; if (r >= M) r = M - 1;          // clamp; masked at C
        long grow;
        if (MODE == 0 && routed) grow = tok[e * T_TOK + r];
        else if (routed)         grow = rbase + r;
        else                     grow = r;
        aptr[i] = Ap + grow * (long)K + ((s ^ (row & 7)) << 3);
    }
    const u16* bptr1[2]; const u16* bptr2[2];
#pragma unroll
    for (int i = 0; i < 2; ++i) {
        int q = i * 256 + tid;
        int row = q >> 3, s = q & 7;
        long go = (long)(n0 + row) * K + ((s ^ (row & 7)) << 3);
        bptr1[i] = B1p + go;
        bptr2[i] = DUAL ? (B2p + go) : B1p;
    }

    f32x4 accG[4][2], accU[4][2];
#pragma unroll
    for (int i = 0; i < 4; ++i)
#pragma unroll
        for (int j = 0; j < 2; ++j) {
            accG[i][j] = (f32x4){0.f, 0.f, 0.f, 0.f};
            if (DUAL) accU[i][j] = (f32x4){0.f, 0.f, 0.f, 0.f};
        }

    auto STAGE = [&](int buf, int kt) {
#pragma unroll
        for (int i = 0; i < 4; ++i) GLOAD16(aptr[i] + kt, &sA[buf][(i * 256 + tid) * 8]);
#pragma unroll
        for (int i = 0; i < 2; ++i) {
            GLOAD16(bptr1[i] + kt, &sB1[buf][(i * 256 + tid) * 8]);
            if (DUAL) GLOAD16(bptr2[i] + kt, &sB2[buf][(i * 256 + tid) * 8]);
        }
    };

    const int nt = K >> 6;
    STAGE(0, 0);
    asm volatile("s_waitcnt vmcnt(0)" ::: "memory");
    __syncthreads();

    int cur = 0;
    for (int t = 0; t < nt; ++t) {
        if (t + 1 < nt) STAGE(cur ^ 1, (t + 1) << 6);    // prefetch next tile

        const u16* sAc  = sA[cur];
        const u16* sB1c = sB1[cur];
        const u16* sB2c = sB2[DUAL ? cur : 0];
#pragma unroll
        for (int ks = 0; ks < 2; ++ks) {
            bf16x8 a[4], bg[2], bu[2];
#pragma unroll
            for (int mf = 0; mf < 4; ++mf) {
                int row = wr * 64 + mf * 16 + (lane & 15);
                int c   = ks * 4 + (lane >> 4);
                a[mf] = __builtin_bit_cast(bf16x8,
                    *(const short8*)&sAc[row * 64 + ((c ^ (row & 7)) << 3)]);
            }
#pragma unroll
            for (int nf = 0; nf < 2; ++nf) {
                int row = wc * 32 + nf * 16 + (lane & 15);
                int c   = ks * 4 + (lane >> 4);
                int o   = row * 64 + ((c ^ (row & 7)) << 3);
                bg[nf] = __builtin_bit_cast(bf16x8, *(const short8*)&sB1c[o]);
                if (DUAL) bu[nf] = __builtin_bit_cast(bf16x8, *(const short8*)&sB2c[o]);
            }
#pragma unroll
            for (int mf = 0; mf < 4; ++mf)
#pragma unroll
                for (int nf = 0; nf < 2; ++nf) {
                    accG[mf][nf] = __builtin_amdgcn_mfma_f32_16x16x32_bf16(
                        a[mf], bg[nf], accG[mf][nf], 0, 0, 0);
                    if (DUAL)
                        accU[mf][nf] = __builtin_amdgcn_mfma_f32_16x16x32_bf16(
                            a[mf], bu[nf], accU[mf][nf], 0, 0, 0);
                }
        }

        if (t + 1 < nt) {
            asm volatile("s_waitcnt vmcnt(0)" ::: "memory");
            __syncthreads();
        }
        cur ^= 1;
    }

    // epilogue: C/D layout col = lane&15, row = (lane>>4)*4 + reg  [m89]
#pragma unroll
    for (int mf = 0; mf < 4; ++mf)
#pragma unroll
        for (int nf = 0; nf < 2; ++nf)
#pragma unroll
            for (int r = 0; r < 4; ++r) {
                int row = m0 + wr * 64 + mf * 16 + (lane >> 4) * 4 + r;
                if (row >= M) continue;
                int col = n0 + wc * 32 + nf * 16 + (lane & 15);
                float v = accG[mf][nf][r];
                if constexpr (DUAL) {
                    float uu = accU[mf][nf][r];
                    v = v / (1.f + expf(-v)) * uu;       // silu(g)*u
                }
                long orow = routed ? (long)(rbase + row) : (long)row;
                if (MODE == 1 && !routed) ((float*)outS)[orow * Ntot + col] = v;
                else if (routed)          outR[orow * Ntot + col] = f2bf(v);
                else                      ((u16*)outS)[orow * Ntot + col] = f2bf(v);
            }
}

// ---------------------------------------------------------------------------
// K5: combine. out[t] (already = shared_out) += sum_k w_k * pair[eb+pos].
// ---------------------------------------------------------------------------
__global__ __launch_bounds__(256) void combine_kernel(
    float* __restrict__ out, const u16* __restrict__ pair,
    const int* __restrict__ slot, const float* __restrict__ wgt,
    const int* __restrict__ cnt)
{
    __shared__ int eb_s[E_NUM];
    if (threadIdx.x < E_NUM) {
        int s = 0;
        for (int i = 0; i < E_NUM; ++i) s += (i < (int)threadIdx.x) ? cnt[CNT(i)] : 0;
        eb_s[threadIdx.x] = s;
    }
    __syncthreads();

    const int t = blockIdx.x;
    const int c = threadIdx.x * 4;
    float4 o = *(float4*)&out[(long)t * H_DIM + c];
#pragma unroll
    for (int k = 0; k < 4; ++k) {
        int s = slot[t * 4 + k];
        int e = s >> 16, pos = s & 0xffff;
        float w = wgt[t * 4 + k];
        const u16* pr = pair + (long)(eb_s[e] + pos) * H_DIM + c;
        U16x4 pv = *(const U16x4*)pr;
        o.x += w * bf2f(pv.x);
        o.y += w * bf2f(pv.y);
        o.z += w * bf2f(pv.z);
        o.w += w * bf2f(pv.w);
    }
    *(float4*)&out[(long)t * H_DIM + c] = o;
}

// ---------------------------------------------------------------------------
extern "C" void kernel_launch(void* const* d_in, const int* in_sizes, int n_in,
                              void* d_out, int out_size, void* d_ws, size_t ws_size,
                              hipStream_t stream)
{
    const float* x  = (const float*)d_in[0];
    const float* gw = (const float*)d_in[1];
    const float* eg = (const float*)d_in[2];
    const float* eu = (const float*)d_in[3];
    const float* ed = (const float*)d_in[4];
    const float* sg = (const float*)d_in[5];
    const float* su = (const float*)d_in[6];
    const float* sd = (const float*)d_in[7];
    float* out = (float*)d_out;

    unsigned char* w = (unsigned char*)d_ws;
    size_t off = 0;
    auto alloc = [&](size_t b) -> void* {
        off = (off + 255) & ~(size_t)255;
        void* p = w + off; off += b; return p;
    };
    int*   cnt  = (int*)  alloc(256 * 4);
    int*   tok  = (int*)  alloc((size_t)E_NUM * T_TOK * 4);
    int*   slot = (int*)  alloc((size_t)T_TOK * 4 * 4);
    float* wgt  = (float*)alloc((size_t)T_TOK * 4 * 4);
    u16*   xb   = (u16*)  alloc((size_t)T_TOK * H_DIM * 2);
    u16*   egT  = (u16*)  alloc((size_t)E_NUM * I_DIM * H_DIM * 2);
    u16*   euT  = (u16*)  alloc((size_t)E_NUM * I_DIM * H_DIM * 2);
    u16*   edT  = (u16*)  alloc((size_t)E_NUM * H_DIM * I_DIM * 2);
    u16*   sgT  = (u16*)  alloc((size_t)SI_DIM * H_DIM * 2);
    u16*   suT  = (u16*)  alloc((size_t)SI_DIM * H_DIM * 2);
    u16*   sdT  = (u16*)  alloc((size_t)H_DIM * SI_DIM * 2);
    u16*   actR = (u16*)  alloc((size_t)T_TOK * 4 * I_DIM * 2);  // 8192 x 512
    u16*   actS = (u16*)  alloc((size_t)T_TOK * SI_DIM * 2);     // 2048 x 1024
    u16*   pair = (u16*)  alloc((size_t)T_TOK * 4 * H_DIM * 2);  // 8192 x 1024

    hipMemsetAsync(cnt, 0, 256 * 4, stream);

    route_kernel<<<T_TOK / 4, 256, 0, stream>>>(x, gw, cnt, tok, slot, wgt, xb);
    transpose_mega<<<6912, 256, 0, stream>>>(eg, eu, ed, sg, su, sd,
                                             egT, euT, edT, sgT, suT, sdT);
    gemm_moe<0><<<2304, 256, 0, stream>>>(xb, nullptr, nullptr,
                                          egT, euT, sgT, suT,
                                          actR, actS, cnt, tok);
    gemm_moe<1><<<4352, 256, 0, stream>>>(nullptr, actR, actS,
                                          edT, nullptr, sdT, nullptr,
                                          pair, out, cnt, nullptr);
    combine_kernel<<<T_TOK, 256, 0, stream>>>(out, pair, slot, wgt, cnt);
}

// Round 3
// 348.559 us; speedup vs baseline: 1.0082x; 1.0082x over previous
//
#include <hip/hip_runtime.h>

// ---------------------------------------------------------------------------
// DeepseekV3 MoE: T=2048 tokens, H=1024, E=16 experts (top-4), I=512, SI=1024
// 4 dispatches: prep (route + 6 transposes), up-GEMM (dual, silu*u),
// down-GEMM, combine. bf16 MFMA, fp32 routing. Single-buffered K-loop
// (32KB LDS -> 3+ blocks/CU; round-2's 64KB double-buffer halved occupancy).
// ---------------------------------------------------------------------------

#define T_TOK 2048
#define H_DIM 1024
#define E_NUM 16
#define I_DIM 512
#define SI_DIM 1024

typedef __bf16 bf16x8 __attribute__((ext_vector_type(8)));
typedef short short8 __attribute__((ext_vector_type(8)));
typedef float f32x4 __attribute__((ext_vector_type(4)));
typedef unsigned short u16;

struct alignas(8) U16x4 { u16 x, y, z, w; };
struct alignas(4) U16x2 { u16 x, y; };

__device__ __forceinline__ float bf2f(u16 u) {
    union { float f; unsigned int i; } v; v.i = ((unsigned int)u) << 16; return v.f;
}
__device__ __forceinline__ u16 f2bf(float f) {
    union { float f; unsigned int i; } v; v.f = f;
    unsigned int i = v.i;
    return (u16)((i + 0x7fffu + ((i >> 16) & 1u)) >> 16);   // RNE
}

#define GLOAD16(g, l)                                                          \
    __builtin_amdgcn_global_load_lds(                                          \
        (const __attribute__((address_space(1))) unsigned int*)(const void*)(g),\
        (__attribute__((address_space(3))) unsigned int*)(void*)(l), 16, 0, 0)

#define CNT(e) ((e) * 16)   // counts padded to one cacheline each

// ---------------------------------------------------------------------------
// K1: prep = 6 transposes (f32 -> bf16 transposed) + routing (+ x->bf16).
// ---------------------------------------------------------------------------
__device__ __forceinline__ void tr_tile(
    const float* __restrict__ in, u16* __restrict__ out,
    int R, int C, int z, int by, int bx)
{
    __shared__ float tl[64][65];
    const long boff = (long)z * R * C;
    const int r0 = by * 64, c0 = bx * 64;
    const int tid = threadIdx.x;

#pragma unroll
    for (int p = 0; p < 16; ++p) {
        int row = p * 4 + (tid >> 6), col = tid & 63;
        tl[row][col] = in[boff + (long)(r0 + row) * C + (c0 + col)];
    }
    __syncthreads();
#pragma unroll
    for (int p = 0; p < 8; ++p) {
        int cc = p * 8 + (tid >> 5), rp = (tid & 31) * 2;
        U16x2 o = { f2bf(tl[rp][cc]), f2bf(tl[rp + 1][cc]) };
        *(U16x2*)&out[boff + (long)(c0 + cc) * R + (r0 + rp)] = o;
    }
}

__device__ __forceinline__ void route_block(
    const float* __restrict__ x, const float* __restrict__ gw,
    int* __restrict__ cnt, int* __restrict__ tok,
    int* __restrict__ slot, float* __restrict__ wgt, u16* __restrict__ xb,
    int blk)
{
    const int wid  = threadIdx.x >> 6;
    const int lane = threadIdx.x & 63;
    const int t    = blk * 4 + wid;

    const float* xp = x + (long)t * H_DIM;
    float xr[16];
#pragma unroll
    for (int j = 0; j < 16; ++j) xr[j] = xp[lane + 64 * j];

#pragma unroll
    for (int j = 0; j < 16; ++j) xb[(long)t * H_DIM + lane + 64 * j] = f2bf(xr[j]);

    float sc[E_NUM];
#pragma unroll
    for (int e = 0; e < E_NUM; ++e) {
        const float* gp = gw + e * H_DIM;
        float d = 0.f;
#pragma unroll
        for (int j = 0; j < 16; ++j) d += xr[j] * gp[lane + 64 * j];
#pragma unroll
        for (int off = 32; off; off >>= 1) d += __shfl_xor(d, off);
        sc[e] = 1.f / (1.f + expf(-d));      // sigmoid
    }

    // top-4, strict > so ties pick lowest index (matches jax top_k)
    float w[4]; int id[4];
    unsigned picked = 0;
    float sum = 0.f;
#pragma unroll
    for (int k = 0; k < 4; ++k) {
        float mv = -1.f; int mi = 0;
#pragma unroll
        for (int e = 0; e < E_NUM; ++e) {
            bool ok = !((picked >> e) & 1u) && (sc[e] > mv);
            mv = ok ? sc[e] : mv;
            mi = ok ? e : mi;
        }
        w[k] = mv; id[k] = mi; picked |= 1u << mi; sum += mv;
    }
    const float inv = 1.f / (sum + 1e-20f);

    if (lane == 0) {
#pragma unroll
        for (int k = 0; k < 4; ++k) {
            int pos = atomicAdd(&cnt[CNT(id[k])], 1);
            tok[id[k] * T_TOK + pos] = t;
            slot[t * 4 + k] = (id[k] << 16) | pos;
            wgt[t * 4 + k]  = w[k] * inv;
        }
    }
}

__global__ __launch_bounds__(256) void prep_kernel(
    const float* __restrict__ x,  const float* __restrict__ gw,
    const float* __restrict__ eg, const float* __restrict__ eu,
    const float* __restrict__ ed, const float* __restrict__ sg,
    const float* __restrict__ su, const float* __restrict__ sd,
    u16* __restrict__ egT, u16* __restrict__ euT, u16* __restrict__ edT,
    u16* __restrict__ sgT, u16* __restrict__ suT, u16* __restrict__ sdT,
    int* __restrict__ cnt, int* __restrict__ tok,
    int* __restrict__ slot, float* __restrict__ wgt, u16* __restrict__ xb)
{
    int b = blockIdx.x;
    if (b < 2048) {                       // eg: [1024][512] per expert
        int z = b >> 7, rem = b & 127;
        tr_tile(eg, egT, H_DIM, I_DIM, z, rem >> 3, rem & 7);
    } else if (b < 4096) {                // eu
        int l = b - 2048; int z = l >> 7, rem = l & 127;
        tr_tile(eu, euT, H_DIM, I_DIM, z, rem >> 3, rem & 7);
    } else if (b < 6144) {                // ed: [512][1024]
        int l = b - 4096; int z = l >> 7, rem = l & 127;
        tr_tile(ed, edT, I_DIM, H_DIM, z, rem >> 4, rem & 15);
    } else if (b < 6400) {                // sg: [1024][1024]
        int l = b - 6144;
        tr_tile(sg, sgT, H_DIM, SI_DIM, 0, l >> 4, l & 15);
    } else if (b < 6656) {                // su
        int l = b - 6400;
        tr_tile(su, suT, H_DIM, SI_DIM, 0, l >> 4, l & 15);
    } else if (b < 6912) {                // sd
        int l = b - 6656;
        tr_tile(sd, sdT, SI_DIM, H_DIM, 0, l >> 4, l & 15);
    } else {                              // routing: 512 blocks, 4 tokens each
        route_block(x, gw, cnt, tok, slot, wgt, xb, b - 6912);
    }
}

// ---------------------------------------------------------------------------
// K2: up-GEMM. Tile 128x64, BK=64, 4 waves (2x2, wave 64x32), DUAL B
// (gate+up), silu(g)*u epilogue. Single-buffer 32KB LDS, chunk-XOR swizzle
// on both sides. Routed (gather via tok) + shared in one grid; m-fastest,
// bijective XCD chunk swizzle.
// ---------------------------------------------------------------------------
__global__ __launch_bounds__(256) void gemm_up(
    const u16* __restrict__ xb,
    const u16* __restrict__ Wr1, const u16* __restrict__ Wr2,
    const u16* __restrict__ Ws1, const u16* __restrict__ Ws2,
    u16* __restrict__ actR, u16* __restrict__ actS,
    const int* __restrict__ cnt, const int* __restrict__ tok)
{
    constexpr int NWG = 2304, CPX = NWG / 8, RB = 2048, PER_E = 128;
    const int bswz = blockIdx.x;
    const int idx  = (bswz & 7) * CPX + (bswz >> 3);

    const bool routed = idx < RB;
    int e = 0, mb, nb;
    if (routed) {
        e = idx / PER_E;
        int rem = idx % PER_E;
        nb = rem >> 4;                    // 0..7  (N=512)
        mb = rem & 15;                    // m fastest
    } else {
        int rem = idx - RB;
        nb = rem >> 4;                    // 0..15 (N=1024)
        mb = rem & 15;
    }

    int M, rbase = 0;
    const u16 *B1p, *B2p;
    int Ntot;
    if (routed) {
        M = cnt[CNT(e)];
        for (int i = 0; i < e; ++i) rbase += cnt[CNT(i)];
        Ntot = I_DIM;
        B1p  = Wr1 + (long)e * (512L * 1024L);
        B2p  = Wr2 + (long)e * (512L * 1024L);
    } else {
        M = T_TOK; Ntot = SI_DIM;
        B1p = Ws1; B2p = Ws2;
    }
    const int m0 = mb * 128;
    if (m0 >= M) return;
    const int n0 = nb * 64;
    const int K  = H_DIM;

    __shared__ __attribute__((aligned(16))) u16 sA[128 * 64];
    __shared__ __attribute__((aligned(16))) u16 sB1[64 * 64];
    __shared__ __attribute__((aligned(16))) u16 sB2[64 * 64];

    const int tid  = threadIdx.x;
    const int lane = tid & 63;
    const int wid  = tid >> 6;
    const int wr   = wid >> 1;
    const int wc   = wid & 1;

    // staging source pointers: slot q -> (row=q>>3, phys chunk s=q&7); fetch
    // global chunk s^(row&7) so linear LDS ends up chunk-swizzled.
    const u16* aptr[4];
#pragma unroll
    for (int i = 0; i < 4; ++i) {
        int q = i * 256 + tid;
        int row = q >> 3, s = q & 7;
        int r = m0 + row; if (r >= M) r = M - 1;          // clamp; masked at C
        long grow = routed ? (long)tok[e * T_TOK + r] : (long)r;
        aptr[i] = xb + grow * (long)K + ((s ^ (row & 7)) << 3);
    }
    const u16* bptr1[2]; const u16* bptr2[2];
#pragma unroll
    for (int i = 0; i < 2; ++i) {
        int q = i * 256 + tid;
        int row = q >> 3, s = q & 7;
        long go = (long)(n0 + row) * K + ((s ^ (row & 7)) << 3);
        bptr1[i] = B1p + go;
        bptr2[i] = B2p + go;
    }

    f32x4 accG[4][2], accU[4][2];
#pragma unroll
    for (int i = 0; i < 4; ++i)
#pragma unroll
        for (int j = 0; j < 2; ++j) {
            accG[i][j] = (f32x4){0.f, 0.f, 0.f, 0.f};
            accU[i][j] = (f32x4){0.f, 0.f, 0.f, 0.f};
        }

    for (int kt = 0; kt < K; kt += 64) {
        __syncthreads();                   // previous tile fully consumed
#pragma unroll
        for (int i = 0; i < 4; ++i) GLOAD16(aptr[i] + kt, &sA[(i * 256 + tid) * 8]);
#pragma unroll
        for (int i = 0; i < 2; ++i) {
            GLOAD16(bptr1[i] + kt, &sB1[(i * 256 + tid) * 8]);
            GLOAD16(bptr2[i] + kt, &sB2[(i * 256 + tid) * 8]);
        }
        asm volatile("s_waitcnt vmcnt(0)" ::: "memory");
        __syncthreads();

#pragma unroll
        for (int ks = 0; ks < 2; ++ks) {
            bf16x8 a[4], bg[2], bu[2];
#pragma unroll
            for (int mf = 0; mf < 4; ++mf) {
                int row = wr * 64 + mf * 16 + (lane & 15);
                int c   = ks * 4 + (lane >> 4);
                a[mf] = __builtin_bit_cast(bf16x8,
                    *(const short8*)&sA[row * 64 + ((c ^ (row & 7)) << 3)]);
            }
#pragma unroll
            for (int nf = 0; nf < 2; ++nf) {
                int row = wc * 32 + nf * 16 + (lane & 15);
                int c   = ks * 4 + (lane >> 4);
                int o   = row * 64 + ((c ^ (row & 7)) << 3);
                bg[nf] = __builtin_bit_cast(bf16x8, *(const short8*)&sB1[o]);
                bu[nf] = __builtin_bit_cast(bf16x8, *(const short8*)&sB2[o]);
            }
#pragma unroll
            for (int mf = 0; mf < 4; ++mf)
#pragma unroll
                for (int nf = 0; nf < 2; ++nf) {
                    accG[mf][nf] = __builtin_amdgcn_mfma_f32_16x16x32_bf16(
                        a[mf], bg[nf], accG[mf][nf], 0, 0, 0);
                    accU[mf][nf] = __builtin_amdgcn_mfma_f32_16x16x32_bf16(
                        a[mf], bu[nf], accU[mf][nf], 0, 0, 0);
                }
        }
    }

    // epilogue: C/D layout col = lane&15, row = (lane>>4)*4 + reg  [m89]
    u16* outp = routed ? actR : actS;
#pragma unroll
    for (int mf = 0; mf < 4; ++mf)
#pragma unroll
        for (int nf = 0; nf < 2; ++nf)
#pragma unroll
            for (int r = 0; r < 4; ++r) {
                int row = m0 + wr * 64 + mf * 16 + (lane >> 4) * 4 + r;
                if (row >= M) continue;
                int col = n0 + wc * 32 + nf * 16 + (lane & 15);
                float g = accG[mf][nf][r];
                float v = g / (1.f + expf(-g)) * accU[mf][nf][r];   // silu(g)*u
                long orow = routed ? (long)(rbase + row) : (long)row;
                outp[orow * Ntot + col] = f2bf(v);
            }
}

// ---------------------------------------------------------------------------
// K3: down-GEMM. m97-style tile 128x128, BK=64, 4 waves (2x2, wave 64x64),
// single B. Routed: actR @ edT^T -> pair (bf16). Shared: actS @ sdT^T ->
// out (fp32, becomes the base for combine).
// ---------------------------------------------------------------------------
__global__ __launch_bounds__(256) void gemm_down(
    const u16* __restrict__ actR, const u16* __restrict__ actS,
    const u16* __restrict__ Wr,   const u16* __restrict__ Ws,
    u16* __restrict__ pair, float* __restrict__ out,
    const int* __restrict__ cnt)
{
    constexpr int NWG = 2176, CPX = NWG / 8, RB = 2048, PER_E = 128;
    const int bswz = blockIdx.x;
    const int idx  = (bswz & 7) * CPX + (bswz >> 3);

    const bool routed = idx < RB;
    int e = 0, mb, nb;
    if (routed) {
        e = idx / PER_E;
        int rem = idx % PER_E;
        nb = rem >> 4;                    // 0..7  (N=1024, 128-tile)
        mb = rem & 15;
    } else {
        int rem = idx - RB;
        nb = rem >> 4;                    // 0..7
        mb = rem & 15;
    }

    int M, K, rbase = 0;
    const u16 *Ap, *Bp;
    if (routed) {
        M = cnt[CNT(e)];
        for (int i = 0; i < e; ++i) rbase += cnt[CNT(i)];
        K  = I_DIM;
        Ap = actR;
        Bp = Wr + (long)e * (512L * 1024L);
    } else {
        M = T_TOK; K = SI_DIM;
        Ap = actS; Bp = Ws;
    }
    const int m0 = mb * 128;
    if (m0 >= M) return;
    const int n0 = nb * 128;

    __shared__ __attribute__((aligned(16))) u16 sA[128 * 64];
    __shared__ __attribute__((aligned(16))) u16 sB[128 * 64];

    const int tid  = threadIdx.x;
    const int lane = tid & 63;
    const int wid  = tid >> 6;
    const int wr   = wid >> 1;
    const int wc   = wid & 1;

    const u16* aptr[4];
#pragma unroll
    for (int i = 0; i < 4; ++i) {
        int q = i * 256 + tid;
        int row = q >> 3, s = q & 7;
        int r = m0 + row; if (r >= M) r = M - 1;
        long grow = routed ? (long)(rbase + r) : (long)r;
        aptr[i] = Ap + grow * (long)K + ((s ^ (row & 7)) << 3);
    }
    const u16* bptr[4];
#pragma unroll
    for (int i = 0; i < 4; ++i) {
        int q = i * 256 + tid;
        int row = q >> 3, s = q & 7;
        bptr[i] = Bp + (long)(n0 + row) * K + ((s ^ (row & 7)) << 3);
    }

    f32x4 acc[4][4];
#pragma unroll
    for (int i = 0; i < 4; ++i)
#pragma unroll
        for (int j = 0; j < 4; ++j) acc[i][j] = (f32x4){0.f, 0.f, 0.f, 0.f};

    for (int kt = 0; kt < K; kt += 64) {
        __syncthreads();
#pragma unroll
        for (int i = 0; i < 4; ++i) GLOAD16(aptr[i] + kt, &sA[(i * 256 + tid) * 8]);
#pragma unroll
        for (int i = 0; i < 4; ++i) GLOAD16(bptr[i] + kt, &sB[(i * 256 + tid) * 8]);
        asm volatile("s_waitcnt vmcnt(0)" ::: "memory");
        __syncthreads();

#pragma unroll
        for (int ks = 0; ks < 2; ++ks) {
            bf16x8 a[4], b[4];
#pragma unroll
            for (int mf = 0; mf < 4; ++mf) {
                int row = wr * 64 + mf * 16 + (lane & 15);
                int c   = ks * 4 + (lane >> 4);
                a[mf] = __builtin_bit_cast(bf16x8,
                    *(const short8*)&sA[row * 64 + ((c ^ (row & 7)) << 3)]);
            }
#pragma unroll
            for (int nf = 0; nf < 4; ++nf) {
                int row = wc * 64 + nf * 16 + (lane & 15);
                int c   = ks * 4 + (lane >> 4);
                b[nf] = __builtin_bit_cast(bf16x8,
                    *(const short8*)&sB[row * 64 + ((c ^ (row & 7)) << 3)]);
            }
#pragma unroll
            for (int mf = 0; mf < 4; ++mf)
#pragma unroll
                for (int nf = 0; nf < 4; ++nf)
                    acc[mf][nf] = __builtin_amdgcn_mfma_f32_16x16x32_bf16(
                        a[mf], b[nf], acc[mf][nf], 0, 0, 0);
        }
    }

#pragma unroll
    for (int mf = 0; mf < 4; ++mf)
#pragma unroll
        for (int nf = 0; nf < 4; ++nf)
#pragma unroll
            for (int r = 0; r < 4; ++r) {
                int row = m0 + wr * 64 + mf * 16 + (lane >> 4) * 4 + r;
                if (row >= M) continue;
                int col = n0 + wc * 64 + nf * 16 + (lane & 15);
                float v = acc[mf][nf][r];
                if (routed) pair[(long)(rbase + row) * H_DIM + col] = f2bf(v);
                else        out[(long)row * H_DIM + col] = v;
            }
}

// ---------------------------------------------------------------------------
// K4: combine. out[t] (already = shared_out) += sum_k w_k * pair[eb+pos].
// ---------------------------------------------------------------------------
__global__ __launch_bounds__(256) void combine_kernel(
    float* __restrict__ out, const u16* __restrict__ pair,
    const int* __restrict__ slot, const float* __restrict__ wgt,
    const int* __restrict__ cnt)
{
    __shared__ int eb_s[E_NUM];
    if (threadIdx.x < E_NUM) {
        int s = 0;
        for (int i = 0; i < E_NUM; ++i) s += (i < (int)threadIdx.x) ? cnt[CNT(i)] : 0;
        eb_s[threadIdx.x] = s;
    }
    __syncthreads();

    const int t = blockIdx.x;
    const int c = threadIdx.x * 4;
    float4 o = *(float4*)&out[(long)t * H_DIM + c];
#pragma unroll
    for (int k = 0; k < 4; ++k) {
        int s = slot[t * 4 + k];
        int e = s >> 16, pos = s & 0xffff;
        float w = wgt[t * 4 + k];
        const u16* pr = pair + (long)(eb_s[e] + pos) * H_DIM + c;
        U16x4 pv = *(const U16x4*)pr;
        o.x += w * bf2f(pv.x);
        o.y += w * bf2f(pv.y);
        o.z += w * bf2f(pv.z);
        o.w += w * bf2f(pv.w);
    }
    *(float4*)&out[(long)t * H_DIM + c] = o;
}

// ---------------------------------------------------------------------------
extern "C" void kernel_launch(void* const* d_in, const int* in_sizes, int n_in,
                              void* d_out, int out_size, void* d_ws, size_t ws_size,
                              hipStream_t stream)
{
    const float* x  = (const float*)d_in[0];
    const float* gw = (const float*)d_in[1];
    const float* eg = (const float*)d_in[2];
    const float* eu = (const float*)d_in[3];
    const float* ed = (const float*)d_in[4];
    const float* sg = (const float*)d_in[5];
    const float* su = (const float*)d_in[6];
    const float* sd = (const float*)d_in[7];
    float* out = (float*)d_out;

    unsigned char* w = (unsigned char*)d_ws;
    size_t off = 0;
    auto alloc = [&](size_t b) -> void* {
        off = (off + 255) & ~(size_t)255;
        void* p = w + off; off += b; return p;
    };
    int*   cnt  = (int*)  alloc(256 * 4);
    int*   tok  = (int*)  alloc((size_t)E_NUM * T_TOK * 4);
    int*   slot = (int*)  alloc((size_t)T_TOK * 4 * 4);
    float* wgt  = (float*)alloc((size_t)T_TOK * 4 * 4);
    u16*   xb   = (u16*)  alloc((size_t)T_TOK * H_DIM * 2);
    u16*   egT  = (u16*)  alloc((size_t)E_NUM * I_DIM * H_DIM * 2);
    u16*   euT  = (u16*)  alloc((size_t)E_NUM * I_DIM * H_DIM * 2);
    u16*   edT  = (u16*)  alloc((size_t)E_NUM * H_DIM * I_DIM * 2);
    u16*   sgT  = (u16*)  alloc((size_t)SI_DIM * H_DIM * 2);
    u16*   suT  = (u16*)  alloc((size_t)SI_DIM * H_DIM * 2);
    u16*   sdT  = (u16*)  alloc((size_t)H_DIM * SI_DIM * 2);
    u16*   actR = (u16*)  alloc((size_t)T_TOK * 4 * I_DIM * 2);  // 8192 x 512
    u16*   actS = (u16*)  alloc((size_t)T_TOK * SI_DIM * 2);     // 2048 x 1024
    u16*   pair = (u16*)  alloc((size_t)T_TOK * 4 * H_DIM * 2);  // 8192 x 1024

    hipMemsetAsync(cnt, 0, 256 * 4, stream);

    prep_kernel<<<7424, 256, 0, stream>>>(x, gw, eg, eu, ed, sg, su, sd,
                                          egT, euT, edT, sgT, suT, sdT,
                                          cnt, tok, slot, wgt, xb);
    gemm_up<<<2304, 256, 0, stream>>>(xb, egT, euT, sgT, suT,
                                      actR, actS, cnt, tok);
    gemm_down<<<2176, 256, 0, stream>>>(actR, actS, edT, sdT,
                                        pair, out, cnt);
    combine_kernel<<<T_TOK, 256, 0, stream>>>(out, pair, slot, wgt, cnt);
}

// Round 4
// 249.198 us; speedup vs baseline: 1.4102x; 1.3987x over previous
//
#include <hip/hip_runtime.h>

// ---------------------------------------------------------------------------
// DeepseekV3 MoE: T=2048 tokens, H=1024, E=16 experts (top-4), I=512, SI=1024
// 4 dispatches: prep (route + 6 transposes), up-GEMM (dual, silu*u),
// down-GEMM, combine. bf16 MFMA, fp32 routing.
// Round-4: COMPACTED GEMM grids (blocks decode (e,mb,nb) from cnt prefix, no
// dead-block clusters -- round-3's grid was 67% dead in 96-block bursts that
// starved the dispatch window to ~1 live block/CU), vectorized prep.
// ---------------------------------------------------------------------------

#define T_TOK 2048
#define H_DIM 1024
#define E_NUM 16
#define I_DIM 512
#define SI_DIM 1024

typedef __bf16 bf16x8 __attribute__((ext_vector_type(8)));
typedef short short8 __attribute__((ext_vector_type(8)));
typedef float f32x4 __attribute__((ext_vector_type(4)));
typedef unsigned short u16;

struct alignas(8)  U16x4 { u16 x, y, z, w; };
struct alignas(16) U16x8 { u16 v[8]; };

__device__ __forceinline__ float bf2f(u16 u) {
    union { float f; unsigned int i; } v; v.i = ((unsigned int)u) << 16; return v.f;
}
__device__ __forceinline__ u16 f2bf(float f) {
    union { float f; unsigned int i; } v; v.f = f;
    unsigned int i = v.i;
    return (u16)((i + 0x7fffu + ((i >> 16) & 1u)) >> 16);   // RNE
}

#define GLOAD16(g, l)                                                          \
    __builtin_amdgcn_global_load_lds(                                          \
        (const __attribute__((address_space(1))) unsigned int*)(const void*)(g),\
        (__attribute__((address_space(3))) unsigned int*)(void*)(l), 16, 0, 0)

#define CNT(e) ((e) * 16)   // counts padded to one cacheline each

// ---------------------------------------------------------------------------
// K1: prep = 6 transposes (f32 -> bf16 transposed) + routing (+ x->bf16).
// tr_tile: 64x64, float4 loads, coalesced 16B transposed stores.
// ---------------------------------------------------------------------------
__device__ __forceinline__ void tr_tile(
    const float* __restrict__ in, u16* __restrict__ out,
    int R, int C, int z, int by, int bx)
{
    __shared__ float tl[64][66];
    const long boff = (long)z * R * C;
    const int r0 = by * 64, c0 = bx * 64;
    const int q = threadIdx.x;

#pragma unroll
    for (int p = 0; p < 4; ++p) {
        int row = p * 16 + (q >> 4);
        int col = (q & 15) * 4;
        float4 v = *(const float4*)&in[boff + (long)(r0 + row) * C + (c0 + col)];
        tl[row][col]     = v.x;
        tl[row][col + 1] = v.y;
        tl[row][col + 2] = v.z;
        tl[row][col + 3] = v.w;
    }
    __syncthreads();
#pragma unroll
    for (int p = 0; p < 2; ++p) {
        int c  = (q >> 3) + p * 32;          // 8 consecutive lanes share c
        int r8 = (q & 7) * 8;                //  -> 128B contiguous per 8 lanes
        U16x8 o;
#pragma unroll
        for (int j = 0; j < 8; ++j) o.v[j] = f2bf(tl[r8 + j][c]);
        *(U16x8*)&out[boff + (long)(c0 + c) * R + (r0 + r8)] = o;
    }
}

__device__ __forceinline__ void route_block(
    const float* __restrict__ x, const float* __restrict__ gw,
    int* __restrict__ cnt, int* __restrict__ tok,
    int* __restrict__ slot, float* __restrict__ wgt, u16* __restrict__ xb,
    int blk)
{
    const int wid  = threadIdx.x >> 6;
    const int lane = threadIdx.x & 63;
    const int t    = blk * 4 + wid;

    const float* xp = x + (long)t * H_DIM;
    float xr[16];
#pragma unroll
    for (int j = 0; j < 16; ++j) xr[j] = xp[lane + 64 * j];

#pragma unroll
    for (int j = 0; j < 16; ++j) xb[(long)t * H_DIM + lane + 64 * j] = f2bf(xr[j]);

    float sc[E_NUM];
#pragma unroll
    for (int e = 0; e < E_NUM; ++e) {
        const float* gp = gw + e * H_DIM;
        float d = 0.f;
#pragma unroll
        for (int j = 0; j < 16; ++j) d += xr[j] * gp[lane + 64 * j];
#pragma unroll
        for (int off = 32; off; off >>= 1) d += __shfl_xor(d, off);
        sc[e] = 1.f / (1.f + expf(-d));      // sigmoid
    }

    // top-4, strict > so ties pick lowest index (matches jax top_k)
    float w[4]; int id[4];
    unsigned picked = 0;
    float sum = 0.f;
#pragma unroll
    for (int k = 0; k < 4; ++k) {
        float mv = -1.f; int mi = 0;
#pragma unroll
        for (int e = 0; e < E_NUM; ++e) {
            bool ok = !((picked >> e) & 1u) && (sc[e] > mv);
            mv = ok ? sc[e] : mv;
            mi = ok ? e : mi;
        }
        w[k] = mv; id[k] = mi; picked |= 1u << mi; sum += mv;
    }
    const float inv = 1.f / (sum + 1e-20f);

    if (lane == 0) {
#pragma unroll
        for (int k = 0; k < 4; ++k) {
            int pos = atomicAdd(&cnt[CNT(id[k])], 1);
            tok[id[k] * T_TOK + pos] = t;
            slot[t * 4 + k] = (id[k] << 16) | pos;
            wgt[t * 4 + k]  = w[k] * inv;
        }
    }
}

__global__ __launch_bounds__(256) void prep_kernel(
    const float* __restrict__ x,  const float* __restrict__ gw,
    const float* __restrict__ eg, const float* __restrict__ eu,
    const float* __restrict__ ed, const float* __restrict__ sg,
    const float* __restrict__ su, const float* __restrict__ sd,
    u16* __restrict__ egT, u16* __restrict__ euT, u16* __restrict__ edT,
    u16* __restrict__ sgT, u16* __restrict__ suT, u16* __restrict__ sdT,
    int* __restrict__ cnt, int* __restrict__ tok,
    int* __restrict__ slot, float* __restrict__ wgt, u16* __restrict__ xb)
{
    int b = blockIdx.x;
    if (b < 2048) {                       // eg: [1024][512] per expert
        int z = b >> 7, rem = b & 127;
        tr_tile(eg, egT, H_DIM, I_DIM, z, rem >> 3, rem & 7);
    } else if (b < 4096) {                // eu
        int l = b - 2048; int z = l >> 7, rem = l & 127;
        tr_tile(eu, euT, H_DIM, I_DIM, z, rem >> 3, rem & 7);
    } else if (b < 6144) {                // ed: [512][1024]
        int l = b - 4096; int z = l >> 7, rem = l & 127;
        tr_tile(ed, edT, I_DIM, H_DIM, z, rem >> 4, rem & 15);
    } else if (b < 6400) {                // sg: [1024][1024]
        int l = b - 6144;
        tr_tile(sg, sgT, H_DIM, SI_DIM, 0, l >> 4, l & 15);
    } else if (b < 6656) {                // su
        int l = b - 6400;
        tr_tile(su, suT, H_DIM, SI_DIM, 0, l >> 4, l & 15);
    } else if (b < 6912) {                // sd
        int l = b - 6656;
        tr_tile(sd, sdT, SI_DIM, H_DIM, 0, l >> 4, l & 15);
    } else {                              // routing: 512 blocks, 4 tokens each
        route_block(x, gw, cnt, tok, slot, wgt, xb, b - 6912);
    }
}

// ---------------------------------------------------------------------------
// K2: up-GEMM. Tile 128x64, BK=64, 4 waves (2x2, wave 64x32), DUAL B
// (gate+up), silu(g)*u epilogue. Single-buffer 32KB LDS, chunk-XOR swizzle.
// COMPACT grid: block decodes (e,mb,nb) from cnt prefix sums; m-fastest
// within expert (consecutive blocks share the B panel); XCD chunk swizzle.
// ---------------------------------------------------------------------------
__global__ __launch_bounds__(256, 3) void gemm_up(
    const u16* __restrict__ xb,
    const u16* __restrict__ Wr1, const u16* __restrict__ Wr2,
    const u16* __restrict__ Ws1, const u16* __restrict__ Ws2,
    u16* __restrict__ actR, u16* __restrict__ actS,
    const int* __restrict__ cnt, const int* __restrict__ tok)
{
    constexpr int NWG = 896, CPX = NWG / 8;
    const int bswz = blockIdx.x;
    int j = (bswz & 7) * CPX + (bswz >> 3);   // XCD-chunk swizzle (bijective)

    // ---- compact work decode ----
    bool routed = false;
    int e = 0, mb = 0, nb = 0, M = 0, rbase = 0;
    {
        int acc = 0, found = 0;
        for (int i = 0; i < E_NUM && !found; ++i) {
            int m   = cnt[CNT(i)];
            int nbk = (m + 127) >> 7;          // ceil(M/128) m-tiles
            int bl  = nbk * 8;                 // x 8 n-tiles (N=512)
            if (j < bl) { routed = true; e = i; M = m; mb = j % nbk; nb = j / nbk; found = 1; }
            else        { j -= bl; acc += m; }
        }
        rbase = acc;
        if (!routed) {
            if (j >= 256) return;              // shared: 16 mb x 16 nb
            M = T_TOK; mb = j & 15; nb = j >> 4;
        }
    }

    const u16 *B1p, *B2p;
    int Ntot;
    if (routed) {
        Ntot = I_DIM;
        B1p  = Wr1 + (long)e * (512L * 1024L);
        B2p  = Wr2 + (long)e * (512L * 1024L);
    } else {
        Ntot = SI_DIM;
        B1p = Ws1; B2p = Ws2;
    }
    const int m0 = mb * 128;
    const int n0 = nb * 64;
    const int K  = H_DIM;

    __shared__ __attribute__((aligned(16))) u16 sA[128 * 64];
    __shared__ __attribute__((aligned(16))) u16 sB1[64 * 64];
    __shared__ __attribute__((aligned(16))) u16 sB2[64 * 64];

    const int tid  = threadIdx.x;
    const int lane = tid & 63;
    const int wid  = tid >> 6;
    const int wr   = wid >> 1;
    const int wc   = wid & 1;

    // staging sources: slot q -> (row=q>>3, phys chunk s=q&7); fetch global
    // chunk s^(row&7) so linear LDS ends up chunk-swizzled (both-sides rule).
    const u16* aptr[4];
#pragma unroll
    for (int i = 0; i < 4; ++i) {
        int q = i * 256 + tid;
        int row = q >> 3, s = q & 7;
        int r = m0 + row; if (r >= M) r = M - 1;          // clamp; masked at C
        long grow = routed ? (long)tok[e * T_TOK + r] : (long)r;
        aptr[i] = xb + grow * (long)K + ((s ^ (row & 7)) << 3);
    }
    const u16* bptr1[2]; const u16* bptr2[2];
#pragma unroll
    for (int i = 0; i < 2; ++i) {
        int q = i * 256 + tid;
        int row = q >> 3, s = q & 7;
        long go = (long)(n0 + row) * K + ((s ^ (row & 7)) << 3);
        bptr1[i] = B1p + go;
        bptr2[i] = B2p + go;
    }

    f32x4 accG[4][2], accU[4][2];
#pragma unroll
    for (int i = 0; i < 4; ++i)
#pragma unroll
        for (int jj = 0; jj < 2; ++jj) {
            accG[i][jj] = (f32x4){0.f, 0.f, 0.f, 0.f};
            accU[i][jj] = (f32x4){0.f, 0.f, 0.f, 0.f};
        }

    for (int kt = 0; kt < K; kt += 64) {
        __syncthreads();                   // previous tile fully consumed
#pragma unroll
        for (int i = 0; i < 4; ++i) GLOAD16(aptr[i] + kt, &sA[(i * 256 + tid) * 8]);
#pragma unroll
        for (int i = 0; i < 2; ++i) {
            GLOAD16(bptr1[i] + kt, &sB1[(i * 256 + tid) * 8]);
            GLOAD16(bptr2[i] + kt, &sB2[(i * 256 + tid) * 8]);
        }
        asm volatile("s_waitcnt vmcnt(0)" ::: "memory");
        __syncthreads();

#pragma unroll
        for (int ks = 0; ks < 2; ++ks) {
            bf16x8 a[4], bg[2], bu[2];
#pragma unroll
            for (int mf = 0; mf < 4; ++mf) {
                int row = wr * 64 + mf * 16 + (lane & 15);
                int c   = ks * 4 + (lane >> 4);
                a[mf] = __builtin_bit_cast(bf16x8,
                    *(const short8*)&sA[row * 64 + ((c ^ (row & 7)) << 3)]);
            }
#pragma unroll
            for (int nf = 0; nf < 2; ++nf) {
                int row = wc * 32 + nf * 16 + (lane & 15);
                int c   = ks * 4 + (lane >> 4);
                int o   = row * 64 + ((c ^ (row & 7)) << 3);
                bg[nf] = __builtin_bit_cast(bf16x8, *(const short8*)&sB1[o]);
                bu[nf] = __builtin_bit_cast(bf16x8, *(const short8*)&sB2[o]);
            }
#pragma unroll
            for (int mf = 0; mf < 4; ++mf)
#pragma unroll
                for (int nf = 0; nf < 2; ++nf) {
                    accG[mf][nf] = __builtin_amdgcn_mfma_f32_16x16x32_bf16(
                        a[mf], bg[nf], accG[mf][nf], 0, 0, 0);
                    accU[mf][nf] = __builtin_amdgcn_mfma_f32_16x16x32_bf16(
                        a[mf], bu[nf], accU[mf][nf], 0, 0, 0);
                }
        }
    }

    // epilogue: C/D layout col = lane&15, row = (lane>>4)*4 + reg  [m89]
    u16* outp = routed ? actR : actS;
#pragma unroll
    for (int mf = 0; mf < 4; ++mf)
#pragma unroll
        for (int nf = 0; nf < 2; ++nf)
#pragma unroll
            for (int r = 0; r < 4; ++r) {
                int row = m0 + wr * 64 + mf * 16 + (lane >> 4) * 4 + r;
                if (row >= M) continue;
                int col = n0 + wc * 32 + nf * 16 + (lane & 15);
                float g = accG[mf][nf][r];
                float v = g / (1.f + expf(-g)) * accU[mf][nf][r];   // silu(g)*u
                long orow = routed ? (long)(rbase + row) : (long)row;
                outp[orow * Ntot + col] = f2bf(v);
            }
}

// ---------------------------------------------------------------------------
// K3: down-GEMM. Tile 128x128, BK=64, 4 waves (2x2, wave 64x64), single B.
// Compact grid like up-GEMM. Routed: actR @ edT^T -> pair (bf16).
// Shared: actS @ sdT^T -> out (fp32, base for combine).
// ---------------------------------------------------------------------------
__global__ __launch_bounds__(256, 3) void gemm_down(
    const u16* __restrict__ actR, const u16* __restrict__ actS,
    const u16* __restrict__ Wr,   const u16* __restrict__ Ws,
    u16* __restrict__ pair, float* __restrict__ out,
    const int* __restrict__ cnt)
{
    constexpr int NWG = 760, CPX = NWG / 8;
    const int bswz = blockIdx.x;
    int j = (bswz & 7) * CPX + (bswz >> 3);

    bool routed = false;
    int e = 0, mb = 0, nb = 0, M = 0, rbase = 0;
    {
        int acc = 0, found = 0;
        for (int i = 0; i < E_NUM && !found; ++i) {
            int m   = cnt[CNT(i)];
            int nbk = (m + 127) >> 7;
            int bl  = nbk * 8;                 // 8 n-tiles (N=1024, 128-tile)
            if (j < bl) { routed = true; e = i; M = m; mb = j % nbk; nb = j / nbk; found = 1; }
            else        { j -= bl; acc += m; }
        }
        rbase = acc;
        if (!routed) {
            if (j >= 128) return;              // shared: 16 mb x 8 nb
            M = T_TOK; mb = j & 15; nb = j >> 4;
        }
    }

    int K;
    const u16 *Ap, *Bp;
    if (routed) {
        K  = I_DIM;
        Ap = actR;
        Bp = Wr + (long)e * (512L * 1024L);
    } else {
        K = SI_DIM;
        Ap = actS; Bp = Ws;
    }
    const int m0 = mb * 128;
    const int n0 = nb * 128;

    __shared__ __attribute__((aligned(16))) u16 sA[128 * 64];
    __shared__ __attribute__((aligned(16))) u16 sB[128 * 64];

    const int tid  = threadIdx.x;
    const int lane = tid & 63;
    const int wid  = tid >> 6;
    const int wr   = wid >> 1;
    const int wc   = wid & 1;

    const u16* aptr[4];
#pragma unroll
    for (int i = 0; i < 4; ++i) {
        int q = i * 256 + tid;
        int row = q >> 3, s = q & 7;
        int r = m0 + row; if (r >= M) r = M - 1;
        long grow = routed ? (long)(rbase + r) : (long)r;
        aptr[i] = Ap + grow * (long)K + ((s ^ (row & 7)) << 3);
    }
    const u16* bptr[4];
#pragma unroll
    for (int i = 0; i < 4; ++i) {
        int q = i * 256 + tid;
        int row = q >> 3, s = q & 7;
        bptr[i] = Bp + (long)(n0 + row) * K + ((s ^ (row & 7)) << 3);
    }

    f32x4 acc[4][4];
#pragma unroll
    for (int i = 0; i < 4; ++i)
#pragma unroll
        for (int jj = 0; jj < 4; ++jj) acc[i][jj] = (f32x4){0.f, 0.f, 0.f, 0.f};

    for (int kt = 0; kt < K; kt += 64) {
        __syncthreads();
#pragma unroll
        for (int i = 0; i < 4; ++i) GLOAD16(aptr[i] + kt, &sA[(i * 256 + tid) * 8]);
#pragma unroll
        for (int i = 0; i < 4; ++i) GLOAD16(bptr[i] + kt, &sB[(i * 256 + tid) * 8]);
        asm volatile("s_waitcnt vmcnt(0)" ::: "memory");
        __syncthreads();

#pragma unroll
        for (int ks = 0; ks < 2; ++ks) {
            bf16x8 a[4], b[4];
#pragma unroll
            for (int mf = 0; mf < 4; ++mf) {
                int row = wr * 64 + mf * 16 + (lane & 15);
                int c   = ks * 4 + (lane >> 4);
                a[mf] = __builtin_bit_cast(bf16x8,
                    *(const short8*)&sA[row * 64 + ((c ^ (row & 7)) << 3)]);
            }
#pragma unroll
            for (int nf = 0; nf < 4; ++nf) {
                int row = wc * 64 + nf * 16 + (lane & 15);
                int c   = ks * 4 + (lane >> 4);
                b[nf] = __builtin_bit_cast(bf16x8,
                    *(const short8*)&sB[row * 64 + ((c ^ (row & 7)) << 3)]);
            }
#pragma unroll
            for (int mf = 0; mf < 4; ++mf)
#pragma unroll
                for (int nf = 0; nf < 4; ++nf)
                    acc[mf][nf] = __builtin_amdgcn_mfma_f32_16x16x32_bf16(
                        a[mf], b[nf], acc[mf][nf], 0, 0, 0);
        }
    }

#pragma unroll
    for (int mf = 0; mf < 4; ++mf)
#pragma unroll
        for (int nf = 0; nf < 4; ++nf)
#pragma unroll
            for (int r = 0; r < 4; ++r) {
                int row = m0 + wr * 64 + mf * 16 + (lane >> 4) * 4 + r;
                if (row >= M) continue;
                int col = n0 + wc * 64 + nf * 16 + (lane & 15);
                float v = acc[mf][nf][r];
                if (routed) pair[(long)(rbase + row) * H_DIM + col] = f2bf(v);
                else        out[(long)row * H_DIM + col] = v;
            }
}

// ---------------------------------------------------------------------------
// K4: combine. out[t] (already = shared_out) += sum_k w_k * pair[eb+pos].
// ---------------------------------------------------------------------------
__global__ __launch_bounds__(256) void combine_kernel(
    float* __restrict__ out, const u16* __restrict__ pair,
    const int* __restrict__ slot, const float* __restrict__ wgt,
    const int* __restrict__ cnt)
{
    __shared__ int eb_s[E_NUM];
    if (threadIdx.x < E_NUM) {
        int s = 0;
        for (int i = 0; i < E_NUM; ++i) s += (i < (int)threadIdx.x) ? cnt[CNT(i)] : 0;
        eb_s[threadIdx.x] = s;
    }
    __syncthreads();

    const int t = blockIdx.x;
    const int c = threadIdx.x * 4;
    float4 o = *(float4*)&out[(long)t * H_DIM + c];
#pragma unroll
    for (int k = 0; k < 4; ++k) {
        int s = slot[t * 4 + k];
        int e = s >> 16, pos = s & 0xffff;
        float w = wgt[t * 4 + k];
        const u16* pr = pair + (long)(eb_s[e] + pos) * H_DIM + c;
        U16x4 pv = *(const U16x4*)pr;
        o.x += w * bf2f(pv.x);
        o.y += w * bf2f(pv.y);
        o.z += w * bf2f(pv.z);
        o.w += w * bf2f(pv.w);
    }
    *(float4*)&out[(long)t * H_DIM + c] = o;
}

// ---------------------------------------------------------------------------
extern "C" void kernel_launch(void* const* d_in, const int* in_sizes, int n_in,
                              void* d_out, int out_size, void* d_ws, size_t ws_size,
                              hipStream_t stream)
{
    const float* x  = (const float*)d_in[0];
    const float* gw = (const float*)d_in[1];
    const float* eg = (const float*)d_in[2];
    const float* eu = (const float*)d_in[3];
    const float* ed = (const float*)d_in[4];
    const float* sg = (const float*)d_in[5];
    const float* su = (const float*)d_in[6];
    const float* sd = (const float*)d_in[7];
    float* out = (float*)d_out;

    unsigned char* w = (unsigned char*)d_ws;
    size_t off = 0;
    auto alloc = [&](size_t b) -> void* {
        off = (off + 255) & ~(size_t)255;
        void* p = w + off; off += b; return p;
    };
    int*   cnt  = (int*)  alloc(256 * 4);
    int*   tok  = (int*)  alloc((size_t)E_NUM * T_TOK * 4);
    int*   slot = (int*)  alloc((size_t)T_TOK * 4 * 4);
    float* wgt  = (float*)alloc((size_t)T_TOK * 4 * 4);
    u16*   xb   = (u16*)  alloc((size_t)T_TOK * H_DIM * 2);
    u16*   egT  = (u16*)  alloc((size_t)E_NUM * I_DIM * H_DIM * 2);
    u16*   euT  = (u16*)  alloc((size_t)E_NUM * I_DIM * H_DIM * 2);
    u16*   edT  = (u16*)  alloc((size_t)E_NUM * H_DIM * I_DIM * 2);
    u16*   sgT  = (u16*)  alloc((size_t)SI_DIM * H_DIM * 2);
    u16*   suT  = (u16*)  alloc((size_t)SI_DIM * H_DIM * 2);
    u16*   sdT  = (u16*)  alloc((size_t)H_DIM * SI_DIM * 2);
    u16*   actR = (u16*)  alloc((size_t)T_TOK * 4 * I_DIM * 2);  // 8192 x 512
    u16*   actS = (u16*)  alloc((size_t)T_TOK * SI_DIM * 2);     // 2048 x 1024
    u16*   pair = (u16*)  alloc((size_t)T_TOK * 4 * H_DIM * 2);  // 8192 x 1024

    hipMemsetAsync(cnt, 0, 256 * 4, stream);

    prep_kernel<<<7424, 256, 0, stream>>>(x, gw, eg, eu, ed, sg, su, sd,
                                          egT, euT, edT, sgT, suT, sdT,
                                          cnt, tok, slot, wgt, xb);
    gemm_up<<<896, 256, 0, stream>>>(xb, egT, euT, sgT, suT,
                                     actR, actS, cnt, tok);
    gemm_down<<<760, 256, 0, stream>>>(actR, actS, edT, sdT,
                                       pair, out, cnt);
    combine_kernel<<<T_TOK, 256, 0, stream>>>(out, pair, slot, wgt, cnt);
}

// Round 5
// 249.064 us; speedup vs baseline: 1.4109x; 1.0005x over previous
//
#include <hip/hip_runtime.h>

// ---------------------------------------------------------------------------
// DeepseekV3 MoE: T=2048 tokens, H=1024, E=16 experts (top-4), I=512, SI=1024
// 4 dispatches: prep (route + 6 transposes), up-GEMM (dual, silu*u),
// down-GEMM, combine. bf16 MFMA, fp32 routing.
// Round-5: barrier-free direct transpose in prep (round-4's LDS version sat
// at 1.8 TB/s from exposed latency: load->sync->scalar-LDS->store chains at
// ~8 waves/CU). Reads strided float4 (L1 amortizes lines), writes 2B/lane
// with 64 consecutive lanes = contiguous 128B per store instr.
// ---------------------------------------------------------------------------

#define T_TOK 2048
#define H_DIM 1024
#define E_NUM 16
#define I_DIM 512
#define SI_DIM 1024

typedef __bf16 bf16x8 __attribute__((ext_vector_type(8)));
typedef short short8 __attribute__((ext_vector_type(8)));
typedef float f32x4 __attribute__((ext_vector_type(4)));
typedef unsigned short u16;

struct alignas(8)  U16x4 { u16 x, y, z, w; };

__device__ __forceinline__ float bf2f(u16 u) {
    union { float f; unsigned int i; } v; v.i = ((unsigned int)u) << 16; return v.f;
}
__device__ __forceinline__ u16 f2bf(float f) {
    union { float f; unsigned int i; } v; v.f = f;
    unsigned int i = v.i;
    return (u16)((i + 0x7fffu + ((i >> 16) & 1u)) >> 16);   // RNE
}

#define GLOAD16(g, l)                                                          \
    __builtin_amdgcn_global_load_lds(                                          \
        (const __attribute__((address_space(1))) unsigned int*)(const void*)(g),\
        (__attribute__((address_space(3))) unsigned int*)(void*)(l), 16, 0, 0)

#define CNT(e) ((e) * 16)   // counts padded to one cacheline each

// ---------------------------------------------------------------------------
// K1: prep = 6 transposes (f32 -> bf16 transposed) + routing (+ x->bf16).
// tr_tile: 64x64, no LDS / no barrier. Lane q owns row r=q&63; wave q>>6
// owns a 16-col group. Reads: float4, 64 lanes stride-C (lines amortized by
// L1 across the p-loop). Writes: u16, 64 lanes hit consecutive r -> 128B
// contiguous per store instruction.
// ---------------------------------------------------------------------------
__device__ __forceinline__ void tr_tile(
    const float* __restrict__ in, u16* __restrict__ out,
    int R, int C, int z, int by, int bx)
{
    const long boff = (long)z * R * C;
    const int r0 = by * 64, c0 = bx * 64;
    const int q = threadIdx.x;
    const int r  = q & 63;            // row within tile (lane-fast)
    const int cb = (q >> 6) * 16;     // this wave's 16-col group

    const float* src = in  + boff + (long)(r0 + r) * C + (c0 + cb);
    u16*         dst = out + boff + (long)(c0 + cb) * R + (r0 + r);

#pragma unroll
    for (int p = 0; p < 4; ++p) {
        float4 v = *(const float4*)&src[p * 4];
        dst[(long)(p * 4 + 0) * R] = f2bf(v.x);
        dst[(long)(p * 4 + 1) * R] = f2bf(v.y);
        dst[(long)(p * 4 + 2) * R] = f2bf(v.z);
        dst[(long)(p * 4 + 3) * R] = f2bf(v.w);
    }
}

__device__ __forceinline__ void route_block(
    const float* __restrict__ x, const float* __restrict__ gw,
    int* __restrict__ cnt, int* __restrict__ tok,
    int* __restrict__ slot, float* __restrict__ wgt, u16* __restrict__ xb,
    int blk)
{
    const int wid  = threadIdx.x >> 6;
    const int lane = threadIdx.x & 63;
    const int t    = blk * 4 + wid;

    const float* xp = x + (long)t * H_DIM;
    float xr[16];
#pragma unroll
    for (int j = 0; j < 16; ++j) xr[j] = xp[lane + 64 * j];

#pragma unroll
    for (int j = 0; j < 16; ++j) xb[(long)t * H_DIM + lane + 64 * j] = f2bf(xr[j]);

    float sc[E_NUM];
#pragma unroll
    for (int e = 0; e < E_NUM; ++e) {
        const float* gp = gw + e * H_DIM;
        float d = 0.f;
#pragma unroll
        for (int j = 0; j < 16; ++j) d += xr[j] * gp[lane + 64 * j];
#pragma unroll
        for (int off = 32; off; off >>= 1) d += __shfl_xor(d, off);
        sc[e] = 1.f / (1.f + expf(-d));      // sigmoid
    }

    // top-4, strict > so ties pick lowest index (matches jax top_k)
    float w[4]; int id[4];
    unsigned picked = 0;
    float sum = 0.f;
#pragma unroll
    for (int k = 0; k < 4; ++k) {
        float mv = -1.f; int mi = 0;
#pragma unroll
        for (int e = 0; e < E_NUM; ++e) {
            bool ok = !((picked >> e) & 1u) && (sc[e] > mv);
            mv = ok ? sc[e] : mv;
            mi = ok ? e : mi;
        }
        w[k] = mv; id[k] = mi; picked |= 1u << mi; sum += mv;
    }
    const float inv = 1.f / (sum + 1e-20f);

    if (lane == 0) {
#pragma unroll
        for (int k = 0; k < 4; ++k) {
            int pos = atomicAdd(&cnt[CNT(id[k])], 1);
            tok[id[k] * T_TOK + pos] = t;
            slot[t * 4 + k] = (id[k] << 16) | pos;
            wgt[t * 4 + k]  = w[k] * inv;
        }
    }
}

__global__ __launch_bounds__(256) void prep_kernel(
    const float* __restrict__ x,  const float* __restrict__ gw,
    const float* __restrict__ eg, const float* __restrict__ eu,
    const float* __restrict__ ed, const float* __restrict__ sg,
    const float* __restrict__ su, const float* __restrict__ sd,
    u16* __restrict__ egT, u16* __restrict__ euT, u16* __restrict__ edT,
    u16* __restrict__ sgT, u16* __restrict__ suT, u16* __restrict__ sdT,
    int* __restrict__ cnt, int* __restrict__ tok,
    int* __restrict__ slot, float* __restrict__ wgt, u16* __restrict__ xb)
{
    int b = blockIdx.x;
    if (b < 2048) {                       // eg: [1024][512] per expert
        int z = b >> 7, rem = b & 127;
        tr_tile(eg, egT, H_DIM, I_DIM, z, rem >> 3, rem & 7);
    } else if (b < 4096) {                // eu
        int l = b - 2048; int z = l >> 7, rem = l & 127;
        tr_tile(eu, euT, H_DIM, I_DIM, z, rem >> 3, rem & 7);
    } else if (b < 6144) {                // ed: [512][1024]
        int l = b - 4096; int z = l >> 7, rem = l & 127;
        tr_tile(ed, edT, I_DIM, H_DIM, z, rem >> 4, rem & 15);
    } else if (b < 6400) {                // sg: [1024][1024]
        int l = b - 6144;
        tr_tile(sg, sgT, H_DIM, SI_DIM, 0, l >> 4, l & 15);
    } else if (b < 6656) {                // su
        int l = b - 6400;
        tr_tile(su, suT, H_DIM, SI_DIM, 0, l >> 4, l & 15);
    } else if (b < 6912) {                // sd
        int l = b - 6656;
        tr_tile(sd, sdT, SI_DIM, H_DIM, 0, l >> 4, l & 15);
    } else {                              // routing: 512 blocks, 4 tokens each
        route_block(x, gw, cnt, tok, slot, wgt, xb, b - 6912);
    }
}

// ---------------------------------------------------------------------------
// K2: up-GEMM. Tile 128x64, BK=64, 4 waves (2x2, wave 64x32), DUAL B
// (gate+up), silu(g)*u epilogue. Single-buffer 32KB LDS, chunk-XOR swizzle.
// COMPACT grid: block decodes (e,mb,nb) from cnt prefix sums; m-fastest
// within expert (consecutive blocks share the B panel); XCD chunk swizzle.
// ---------------------------------------------------------------------------
__global__ __launch_bounds__(256, 3) void gemm_up(
    const u16* __restrict__ xb,
    const u16* __restrict__ Wr1, const u16* __restrict__ Wr2,
    const u16* __restrict__ Ws1, const u16* __restrict__ Ws2,
    u16* __restrict__ actR, u16* __restrict__ actS,
    const int* __restrict__ cnt, const int* __restrict__ tok)
{
    constexpr int NWG = 896, CPX = NWG / 8;
    const int bswz = blockIdx.x;
    int j = (bswz & 7) * CPX + (bswz >> 3);   // XCD-chunk swizzle (bijective)

    // ---- compact work decode ----
    bool routed = false;
    int e = 0, mb = 0, nb = 0, M = 0, rbase = 0;
    {
        int acc = 0, found = 0;
        for (int i = 0; i < E_NUM && !found; ++i) {
            int m   = cnt[CNT(i)];
            int nbk = (m + 127) >> 7;          // ceil(M/128) m-tiles
            int bl  = nbk * 8;                 // x 8 n-tiles (N=512)
            if (j < bl) { routed = true; e = i; M = m; mb = j % nbk; nb = j / nbk; found = 1; }
            else        { j -= bl; acc += m; }
        }
        rbase = acc;
        if (!routed) {
            if (j >= 256) return;              // shared: 16 mb x 16 nb
            M = T_TOK; mb = j & 15; nb = j >> 4;
        }
    }

    const u16 *B1p, *B2p;
    int Ntot;
    if (routed) {
        Ntot = I_DIM;
        B1p  = Wr1 + (long)e * (512L * 1024L);
        B2p  = Wr2 + (long)e * (512L * 1024L);
    } else {
        Ntot = SI_DIM;
        B1p = Ws1; B2p = Ws2;
    }
    const int m0 = mb * 128;
    const int n0 = nb * 64;
    const int K  = H_DIM;

    __shared__ __attribute__((aligned(16))) u16 sA[128 * 64];
    __shared__ __attribute__((aligned(16))) u16 sB1[64 * 64];
    __shared__ __attribute__((aligned(16))) u16 sB2[64 * 64];

    const int tid  = threadIdx.x;
    const int lane = tid & 63;
    const int wid  = tid >> 6;
    const int wr   = wid >> 1;
    const int wc   = wid & 1;

    // staging sources: slot q -> (row=q>>3, phys chunk s=q&7); fetch global
    // chunk s^(row&7) so linear LDS ends up chunk-swizzled (both-sides rule).
    const u16* aptr[4];
#pragma unroll
    for (int i = 0; i < 4; ++i) {
        int q = i * 256 + tid;
        int row = q >> 3, s = q & 7;
        int r = m0 + row; if (r >= M) r = M - 1;          // clamp; masked at C
        long grow = routed ? (long)tok[e * T_TOK + r] : (long)r;
        aptr[i] = xb + grow * (long)K + ((s ^ (row & 7)) << 3);
    }
    const u16* bptr1[2]; const u16* bptr2[2];
#pragma unroll
    for (int i = 0; i < 2; ++i) {
        int q = i * 256 + tid;
        int row = q >> 3, s = q & 7;
        long go = (long)(n0 + row) * K + ((s ^ (row & 7)) << 3);
        bptr1[i] = B1p + go;
        bptr2[i] = B2p + go;
    }

    f32x4 accG[4][2], accU[4][2];
#pragma unroll
    for (int i = 0; i < 4; ++i)
#pragma unroll
        for (int jj = 0; jj < 2; ++jj) {
            accG[i][jj] = (f32x4){0.f, 0.f, 0.f, 0.f};
            accU[i][jj] = (f32x4){0.f, 0.f, 0.f, 0.f};
        }

    for (int kt = 0; kt < K; kt += 64) {
        __syncthreads();                   // previous tile fully consumed
#pragma unroll
        for (int i = 0; i < 4; ++i) GLOAD16(aptr[i] + kt, &sA[(i * 256 + tid) * 8]);
#pragma unroll
        for (int i = 0; i < 2; ++i) {
            GLOAD16(bptr1[i] + kt, &sB1[(i * 256 + tid) * 8]);
            GLOAD16(bptr2[i] + kt, &sB2[(i * 256 + tid) * 8]);
        }
        asm volatile("s_waitcnt vmcnt(0)" ::: "memory");
        __syncthreads();

#pragma unroll
        for (int ks = 0; ks < 2; ++ks) {
            bf16x8 a[4], bg[2], bu[2];
#pragma unroll
            for (int mf = 0; mf < 4; ++mf) {
                int row = wr * 64 + mf * 16 + (lane & 15);
                int c   = ks * 4 + (lane >> 4);
                a[mf] = __builtin_bit_cast(bf16x8,
                    *(const short8*)&sA[row * 64 + ((c ^ (row & 7)) << 3)]);
            }
#pragma unroll
            for (int nf = 0; nf < 2; ++nf) {
                int row = wc * 32 + nf * 16 + (lane & 15);
                int c   = ks * 4 + (lane >> 4);
                int o   = row * 64 + ((c ^ (row & 7)) << 3);
                bg[nf] = __builtin_bit_cast(bf16x8, *(const short8*)&sB1[o]);
                bu[nf] = __builtin_bit_cast(bf16x8, *(const short8*)&sB2[o]);
            }
#pragma unroll
            for (int mf = 0; mf < 4; ++mf)
#pragma unroll
                for (int nf = 0; nf < 2; ++nf) {
                    accG[mf][nf] = __builtin_amdgcn_mfma_f32_16x16x32_bf16(
                        a[mf], bg[nf], accG[mf][nf], 0, 0, 0);
                    accU[mf][nf] = __builtin_amdgcn_mfma_f32_16x16x32_bf16(
                        a[mf], bu[nf], accU[mf][nf], 0, 0, 0);
                }
        }
    }

    // epilogue: C/D layout col = lane&15, row = (lane>>4)*4 + reg  [m89]
    u16* outp = routed ? actR : actS;
#pragma unroll
    for (int mf = 0; mf < 4; ++mf)
#pragma unroll
        for (int nf = 0; nf < 2; ++nf)
#pragma unroll
            for (int r = 0; r < 4; ++r) {
                int row = m0 + wr * 64 + mf * 16 + (lane >> 4) * 4 + r;
                if (row >= M) continue;
                int col = n0 + wc * 32 + nf * 16 + (lane & 15);
                float g = accG[mf][nf][r];
                float v = g / (1.f + expf(-g)) * accU[mf][nf][r];   // silu(g)*u
                long orow = routed ? (long)(rbase + row) : (long)row;
                outp[orow * Ntot + col] = f2bf(v);
            }
}

// ---------------------------------------------------------------------------
// K3: down-GEMM. Tile 128x128, BK=64, 4 waves (2x2, wave 64x64), single B.
// Compact grid like up-GEMM. Routed: actR @ edT^T -> pair (bf16).
// Shared: actS @ sdT^T -> out (fp32, base for combine).
// ---------------------------------------------------------------------------
__global__ __launch_bounds__(256, 3) void gemm_down(
    const u16* __restrict__ actR, const u16* __restrict__ actS,
    const u16* __restrict__ Wr,   const u16* __restrict__ Ws,
    u16* __restrict__ pair, float* __restrict__ out,
    const int* __restrict__ cnt)
{
    constexpr int NWG = 760, CPX = NWG / 8;
    const int bswz = blockIdx.x;
    int j = (bswz & 7) * CPX + (bswz >> 3);

    bool routed = false;
    int e = 0, mb = 0, nb = 0, M = 0, rbase = 0;
    {
        int acc = 0, found = 0;
        for (int i = 0; i < E_NUM && !found; ++i) {
            int m   = cnt[CNT(i)];
            int nbk = (m + 127) >> 7;
            int bl  = nbk * 8;                 // 8 n-tiles (N=1024, 128-tile)
            if (j < bl) { routed = true; e = i; M = m; mb = j % nbk; nb = j / nbk; found = 1; }
            else        { j -= bl; acc += m; }
        }
        rbase = acc;
        if (!routed) {
            if (j >= 128) return;              // shared: 16 mb x 8 nb
            M = T_TOK; mb = j & 15; nb = j >> 4;
        }
    }

    int K;
    const u16 *Ap, *Bp;
    if (routed) {
        K  = I_DIM;
        Ap = actR;
        Bp = Wr + (long)e * (512L * 1024L);
    } else {
        K = SI_DIM;
        Ap = actS; Bp = Ws;
    }
    const int m0 = mb * 128;
    const int n0 = nb * 128;

    __shared__ __attribute__((aligned(16))) u16 sA[128 * 64];
    __shared__ __attribute__((aligned(16))) u16 sB[128 * 64];

    const int tid  = threadIdx.x;
    const int lane = tid & 63;
    const int wid  = tid >> 6;
    const int wr   = wid >> 1;
    const int wc   = wid & 1;

    const u16* aptr[4];
#pragma unroll
    for (int i = 0; i < 4; ++i) {
        int q = i * 256 + tid;
        int row = q >> 3, s = q & 7;
        int r = m0 + row; if (r >= M) r = M - 1;
        long grow = routed ? (long)(rbase + r) : (long)r;
        aptr[i] = Ap + grow * (long)K + ((s ^ (row & 7)) << 3);
    }
    const u16* bptr[4];
#pragma unroll
    for (int i = 0; i < 4; ++i) {
        int q = i * 256 + tid;
        int row = q >> 3, s = q & 7;
        bptr[i] = Bp + (long)(n0 + row) * K + ((s ^ (row & 7)) << 3);
    }

    f32x4 acc[4][4];
#pragma unroll
    for (int i = 0; i < 4; ++i)
#pragma unroll
        for (int jj = 0; jj < 4; ++jj) acc[i][jj] = (f32x4){0.f, 0.f, 0.f, 0.f};

    for (int kt = 0; kt < K; kt += 64) {
        __syncthreads();
#pragma unroll
        for (int i = 0; i < 4; ++i) GLOAD16(aptr[i] + kt, &sA[(i * 256 + tid) * 8]);
#pragma unroll
        for (int i = 0; i < 4; ++i) GLOAD16(bptr[i] + kt, &sB[(i * 256 + tid) * 8]);
        asm volatile("s_waitcnt vmcnt(0)" ::: "memory");
        __syncthreads();

#pragma unroll
        for (int ks = 0; ks < 2; ++ks) {
            bf16x8 a[4], b[4];
#pragma unroll
            for (int mf = 0; mf < 4; ++mf) {
                int row = wr * 64 + mf * 16 + (lane & 15);
                int c   = ks * 4 + (lane >> 4);
                a[mf] = __builtin_bit_cast(bf16x8,
                    *(const short8*)&sA[row * 64 + ((c ^ (row & 7)) << 3)]);
            }
#pragma unroll
            for (int nf = 0; nf < 4; ++nf) {
                int row = wc * 64 + nf * 16 + (lane & 15);
                int c   = ks * 4 + (lane >> 4);
                b[nf] = __builtin_bit_cast(bf16x8,
                    *(const short8*)&sB[row * 64 + ((c ^ (row & 7)) << 3)]);
            }
#pragma unroll
            for (int mf = 0; mf < 4; ++mf)
#pragma unroll
                for (int nf = 0; nf < 4; ++nf)
                    acc[mf][nf] = __builtin_amdgcn_mfma_f32_16x16x32_bf16(
                        a[mf], b[nf], acc[mf][nf], 0, 0, 0);
        }
    }

#pragma unroll
    for (int mf = 0; mf < 4; ++mf)
#pragma unroll
        for (int nf = 0; nf < 4; ++nf)
#pragma unroll
            for (int r = 0; r < 4; ++r) {
                int row = m0 + wr * 64 + mf * 16 + (lane >> 4) * 4 + r;
                if (row >= M) continue;
                int col = n0 + wc * 64 + nf * 16 + (lane & 15);
                float v = acc[mf][nf][r];
                if (routed) pair[(long)(rbase + row) * H_DIM + col] = f2bf(v);
                else        out[(long)row * H_DIM + col] = v;
            }
}

// ---------------------------------------------------------------------------
// K4: combine. out[t] (already = shared_out) += sum_k w_k * pair[eb+pos].
// ---------------------------------------------------------------------------
__global__ __launch_bounds__(256) void combine_kernel(
    float* __restrict__ out, const u16* __restrict__ pair,
    const int* __restrict__ slot, const float* __restrict__ wgt,
    const int* __restrict__ cnt)
{
    __shared__ int eb_s[E_NUM];
    if (threadIdx.x < E_NUM) {
        int s = 0;
        for (int i = 0; i < E_NUM; ++i) s += (i < (int)threadIdx.x) ? cnt[CNT(i)] : 0;
        eb_s[threadIdx.x] = s;
    }
    __syncthreads();

    const int t = blockIdx.x;
    const int c = threadIdx.x * 4;
    float4 o = *(float4*)&out[(long)t * H_DIM + c];
#pragma unroll
    for (int k = 0; k < 4; ++k) {
        int s = slot[t * 4 + k];
        int e = s >> 16, pos = s & 0xffff;
        float w = wgt[t * 4 + k];
        const u16* pr = pair + (long)(eb_s[e] + pos) * H_DIM + c;
        U16x4 pv = *(const U16x4*)pr;
        o.x += w * bf2f(pv.x);
        o.y += w * bf2f(pv.y);
        o.z += w * bf2f(pv.z);
        o.w += w * bf2f(pv.w);
    }
    *(float4*)&out[(long)t * H_DIM + c] = o;
}

// ---------------------------------------------------------------------------
extern "C" void kernel_launch(void* const* d_in, const int* in_sizes, int n_in,
                              void* d_out, int out_size, void* d_ws, size_t ws_size,
                              hipStream_t stream)
{
    const float* x  = (const float*)d_in[0];
    const float* gw = (const float*)d_in[1];
    const float* eg = (const float*)d_in[2];
    const float* eu = (const float*)d_in[3];
    const float* ed = (const float*)d_in[4];
    const float* sg = (const float*)d_in[5];
    const float* su = (const float*)d_in[6];
    const float* sd = (const float*)d_in[7];
    float* out = (float*)d_out;

    unsigned char* w = (unsigned char*)d_ws;
    size_t off = 0;
    auto alloc = [&](size_t b) -> void* {
        off = (off + 255) & ~(size_t)255;
        void* p = w + off; off += b; return p;
    };
    int*   cnt  = (int*)  alloc(256 * 4);
    int*   tok  = (int*)  alloc((size_t)E_NUM * T_TOK * 4);
    int*   slot = (int*)  alloc((size_t)T_TOK * 4 * 4);
    float* wgt  = (float*)alloc((size_t)T_TOK * 4 * 4);
    u16*   xb   = (u16*)  alloc((size_t)T_TOK * H_DIM * 2);
    u16*   egT  = (u16*)  alloc((size_t)E_NUM * I_DIM * H_DIM * 2);
    u16*   euT  = (u16*)  alloc((size_t)E_NUM * I_DIM * H_DIM * 2);
    u16*   edT  = (u16*)  alloc((size_t)E_NUM * H_DIM * I_DIM * 2);
    u16*   sgT  = (u16*)  alloc((size_t)SI_DIM * H_DIM * 2);
    u16*   suT  = (u16*)  alloc((size_t)SI_DIM * H_DIM * 2);
    u16*   sdT  = (u16*)  alloc((size_t)H_DIM * SI_DIM * 2);
    u16*   actR = (u16*)  alloc((size_t)T_TOK * 4 * I_DIM * 2);  // 8192 x 512
    u16*   actS = (u16*)  alloc((size_t)T_TOK * SI_DIM * 2);     // 2048 x 1024
    u16*   pair = (u16*)  alloc((size_t)T_TOK * 4 * H_DIM * 2);  // 8192 x 1024

    hipMemsetAsync(cnt, 0, 256 * 4, stream);

    prep_kernel<<<7424, 256, 0, stream>>>(x, gw, eg, eu, ed, sg, su, sd,
                                          egT, euT, edT, sgT, suT, sdT,
                                          cnt, tok, slot, wgt, xb);
    gemm_up<<<896, 256, 0, stream>>>(xb, egT, euT, sgT, suT,
                                     actR, actS, cnt, tok);
    gemm_down<<<760, 256, 0, stream>>>(actR, actS, edT, sdT,
                                       pair, out, cnt);
    combine_kernel<<<T_TOK, 256, 0, stream>>>(out, pair, slot, wgt, cnt);
}